// Round 8
// baseline (1342.991 us; speedup 1.0000x reference)
//
#include <hip/hip_runtime.h>
#include <cstdint>
#include <cstddef>

#define BATCH   65536
#define RANK_K  32769   // sorted_desc[32768] == 32769-th largest (1-indexed)

// direct global->LDS async copy, 16B per lane (dest = wave-uniform base + lane*16; source per-lane)
__device__ __forceinline__ void glds16(const float* gsrc, float* ldst)
{
    __builtin_amdgcn_global_load_lds(
        (const __attribute__((address_space(1))) void*)gsrc,
        (__attribute__((address_space(3))) void*)ldst,
        16, 0, 0);
}

// ============ big GEMM (layers 1&2): C = relu((A*rowmask) @ B + bias), + per-row sum-of-squares partials ============
// v8 (resubmit after infra failure): BM=256, BN=128, BK=16, 256 threads, 8x16/thread (acc=128, AGPR-proven),
// glds staging (v7 shell).
//   Round-6 diagnosis: per-tile 17k cyc == LDS 9216 + FMA 8192 ADDITIVE (zero overlap) -- barrier-aligned
//   waves burst all fragment reads, then all FMA.  v8 interleaves reads INTO the FMA stream:
//     per q: hold A-fragment (8 b128, 32 regs) for the whole q; B double-buffered per kk with STATIC
//     names:  bA<-kk0; A; bB<-kk1; FMA0(bA); bA<-kk2; FMA1(bB); bB<-kk3; FMA2(bA); FMA3(bB)
//   -> each LOADB issued one 256-cyc FMA block before use; LDS services under VALU issue.
//   Swizzles (both-sides involutions):
//     A: LDS row p holds logical row (p&~7)|((p&7)^((p>>3)&7)); read at tr*8+(i^(tr&7)); 8-lane service
//        groups share tr -> broadcast (round-6 measured 0 conflicts with this scheme).
//     B: LDS granule p holds source chunk p^((p>>3)&3); read granule (4tc+o)^((tc>>1)&3) -> 8 distinct quads.
// BIT-EXACTNESS: per-element k-chain is q-major, kkk 0..3 ascending, single-register fmaf (unchanged);
// bias->relu->square identical; norm partial groups: thread's 16 cols = old groups {2tc, 2tc+1}, red[][17]
// filled with identical values in identical slots, summed x=0..15 ascending; layer-2 mask in epilogue
// (m in {0,1}) validated bit-exact in v7.  Masks cannot flip.
template<bool MASKED>
__global__ __launch_bounds__(256, 2)
void gemm_relu_norm(const float* __restrict__ A, const float* __restrict__ B,
                    const float* __restrict__ bias, const float* __restrict__ mask,
                    float* __restrict__ C, float* __restrict__ normPart,
                    const int N, const int K)
{
    __shared__ float As[2][4][256][4];   // [buf][kquad][row (swizzled)][k-in-quad]  (32 KB)
    __shared__ float Bs[2][16][128];     // [buf][krow][col (granule-swizzled)]      (16 KB)

    const int t    = threadIdx.x;
    const int tr   = t >> 3;          // 0..31 row group (8 rows each)
    const int tc   = t & 7;           // 0..7 col group (16 cols each)
    const int amk  = tr & 7;          // A-read row-swizzle key
    const int w    = t >> 6;          // wave id 0..3
    const int row0 = blockIdx.x * 256;
    const int col0 = blockIdx.y * 128;

    // glds A source: lane deposits LDS row-granule t (within wave chunk); granule p holds
    // logical row (p&~7)|((p&7)^((p>>3)&7))  (involution, bits>=3 preserved)
    const int asrow = (t & ~7) | ((t & 7) ^ ((t >> 3) & 7));
    const float* Asrc = A + (size_t)(row0 + asrow) * K;          // + k0 + g*4 per call
    // glds B source: instr h covers k-rows {w*4+2h, w*4+2h+1}; lane l -> row +(l>>5),
    // col chunk swz(l&31), swz(g)=g^((g>>3)&3)  (LDS granule p holds source chunk swz(p))
    const int gB   = t & 31;
    const int brow = w * 4 + ((t >> 5) & 1);
    const int bcol = col0 + 4 * (gB ^ ((gB >> 3) & 3));
    const float* Bsrc = B + (size_t)brow * N + bcol;             // + (k0 + 2h)*N per call

    // B read offsets (float): chunk 4tc+o stored at granule (4tc+o)^((tc>>1)&3)
    const int bkey = (tc >> 1) & 3;
    const int bg0 = 4 * ((4 * tc + 0) ^ bkey);
    const int bg1 = 4 * ((4 * tc + 1) ^ bkey);
    const int bg2 = 4 * ((4 * tc + 2) ^ bkey);
    const int bg3 = 4 * ((4 * tc + 3) ^ bkey);

    float acc[8][16];
    #pragma unroll
    for (int i = 0; i < 8; ++i)
        #pragma unroll
        for (int j = 0; j < 16; ++j) acc[i][j] = 0.0f;

    const int nT = K >> 4;

    // ---- prologue: stage tile 0 into buf 0 ----
    #pragma unroll
    for (int g = 0; g < 4; ++g)
        glds16(Asrc + g * 4, &As[0][g][w * 64][0]);
    glds16(Bsrc,                 &Bs[0][w * 4][0]);
    glds16(Bsrc + 2 * (size_t)N, &Bs[0][w * 4 + 2][0]);

#define LOADB(buf, kk)                                                  \
    *(float4*)&buf[0]  = *(const float4*)&Bs[cur][kk][bg0];             \
    *(float4*)&buf[4]  = *(const float4*)&Bs[cur][kk][bg1];             \
    *(float4*)&buf[8]  = *(const float4*)&Bs[cur][kk][bg2];             \
    *(float4*)&buf[12] = *(const float4*)&Bs[cur][kk][bg3];

#define FMAS(kkk, buf)                                                  \
    _Pragma("unroll")                                                   \
    for (int i = 0; i < 8; ++i)                                         \
        _Pragma("unroll")                                               \
        for (int j = 0; j < 16; ++j)                                    \
            acc[i][j] = fmaf(a_[i][kkk], buf[j], acc[i][j]);

    for (int tile = 0; tile < nT; ++tile) {
        const int cur = tile & 1;
        __syncthreads();   // drains this tile's glds (vmcnt0); 'cur' buffers ready

        if (tile + 1 < nT) {             // issue next-tile staging into the other buffer
            const int nxt = cur ^ 1;
            const int k0n = (tile + 1) << 4;
            #pragma unroll
            for (int g = 0; g < 4; ++g)
                glds16(Asrc + k0n + g * 4, &As[nxt][g][w * 64][0]);
            glds16(Bsrc + (size_t)k0n * N,       &Bs[nxt][w * 4][0]);
            glds16(Bsrc + (size_t)(k0n + 2) * N, &Bs[nxt][w * 4 + 2][0]);
        }

        // ---- compute current tile: per q hold A, double-buffer B, reads interleaved ----
        #pragma unroll 1
        for (int q = 0; q < 4; ++q) {
            const int kb = q * 4;
            float a_[8][4], bA[16], bB[16];
            LOADB(bA, kb + 0)
            #pragma unroll
            for (int i = 0; i < 8; ++i)
                *(float4*)&a_[i][0] = *(const float4*)&As[cur][q][tr * 8 + (i ^ amk)][0];
            LOADB(bB, kb + 1)
            FMAS(0, bA)                  // k = kb+0
            LOADB(bA, kb + 2)            // services under FMA1
            FMAS(1, bB)                  // k = kb+1
            LOADB(bB, kb + 3)            // services under FMA2
            FMAS(2, bA)                  // k = kb+2
            FMAS(3, bB)                  // k = kb+3
        }
    }
#undef LOADB
#undef FMAS

    float bv[16];
    #pragma unroll
    for (int o = 0; o < 4; ++o)
        *(float4*)&bv[o * 4] = *(const float4*)&bias[col0 + tc * 16 + o * 4];

    float mrow[8];
    if (MASKED) {
        *(float4*)&mrow[0] = *(const float4*)&mask[row0 + tr * 8];
        *(float4*)&mrow[4] = *(const float4*)&mask[row0 + tr * 8 + 4];
    }

    // bias -> relu; per-row group sums (j 0..7 = old group 2tc, j 8..15 = old group 2tc+1)
    float slo[8], shi[8];
    #pragma unroll
    for (int i = 0; i < 8; ++i) {
        #pragma unroll
        for (int j = 0; j < 16; ++j) {
            float pv = MASKED ? acc[i][j] * mrow[i] : acc[i][j];  // exact: m in {0,1}
            acc[i][j] = fmaxf(pv + bv[j], 0.0f);                  // +bias, relu (matches ref)
        }
        float s = 0.0f;
        #pragma unroll
        for (int j = 0; j < 8; ++j) s = fmaf(acc[i][j], acc[i][j], s);
        slo[i] = s;
        s = 0.0f;
        #pragma unroll
        for (int j = 8; j < 16; ++j) s = fmaf(acc[i][j], acc[i][j], s);
        shi[i] = s;
    }

    #pragma unroll
    for (int i = 0; i < 8; ++i) {
        const size_t row = (size_t)(row0 + tr * 8 + i);
        *(float4*)&C[row * N + col0 + tc * 16]      = *(float4*)&acc[i][0];
        *(float4*)&C[row * N + col0 + tc * 16 + 4]  = *(float4*)&acc[i][4];
        *(float4*)&C[row * N + col0 + tc * 16 + 8]  = *(float4*)&acc[i][8];
        *(float4*)&C[row * N + col0 + tc * 16 + 12] = *(float4*)&acc[i][12];
    }

    // red aliases the (now dead) A buffers: 256*17*4 = 17408 B <= 32768 B
    __syncthreads();                       // all waves done reading As/Bs
    float (*red)[17] = (float (*)[17])(&As[0][0][0][0]);
    #pragma unroll
    for (int i = 0; i < 8; ++i) {
        red[tr * 8 + i][2 * tc]     = slo[i];
        red[tr * 8 + i][2 * tc + 1] = shi[i];
    }
    __syncthreads();
    {
        float s = 0.0f;
        #pragma unroll
        for (int x = 0; x < 16; ++x) s += red[t][x];    // fixed ascending order -> deterministic
        normPart[(size_t)blockIdx.y * BATCH + row0 + t] = s;
    }
}

// ============ fused: partial-sum -> norm -> exact 32769-th-largest -> mask ============
// NPART>=1: src = part[NPART][BATCH]; norm = sqrt((double)sum_p part[p][i]), p ascending
//           (chain identical to the old reduce_norms_kernel -> bit-identical norms).
// NPART==0: src = norms (already sqrt'd by layer3/layer4 kernels), used directly.
template<int NPART>
__global__ __launch_bounds__(1024)
void select_kernel(const float* __restrict__ src, float* __restrict__ maskOut,
                   float* __restrict__ thrOut)
{
    __shared__ int wsum[16];

    const int t = threadIdx.x;
    unsigned key[64];
    #pragma unroll
    for (int i = 0; i < 16; ++i) {
        float4 v;
        if (NPART == 0) {
            v = ((const float4*)src)[i * 1024 + t];
        } else {
            float4 s = ((const float4*)src)[i * 1024 + t];
            #pragma unroll
            for (int p = 1; p < NPART; ++p) {
                float4 w = ((const float4*)(src + (size_t)p * BATCH))[i * 1024 + t];
                s.x += w.x; s.y += w.y; s.z += w.z; s.w += w.w;   // p ascending, matches old
            }
            v.x = (float)sqrt((double)s.x);
            v.y = (float)sqrt((double)s.y);
            v.z = (float)sqrt((double)s.z);
            v.w = (float)sqrt((double)s.w);
        }
        key[i*4+0] = __float_as_uint(v.x);
        key[i*4+1] = __float_as_uint(v.y);
        key[i*4+2] = __float_as_uint(v.z);
        key[i*4+3] = __float_as_uint(v.w);      // nonneg floats -> monotone uint order
    }

    // V = min{ T : count(key > T) < RANK_K }  == exact RANK_K-th largest value
    unsigned lo = 0u, hi = 0x7F800000u;
    while (lo < hi) {                            // uniform across all threads
        const unsigned mid = lo + ((hi - lo) >> 1);
        int c = 0;
        #pragma unroll
        for (int i = 0; i < 64; ++i) c += (key[i] > mid) ? 1 : 0;
        #pragma unroll
        for (int off = 32; off > 0; off >>= 1) c += __shfl_down(c, off, 64);
        if ((t & 63) == 0) wsum[t >> 6] = c;
        __syncthreads();
        int total = 0;
        #pragma unroll
        for (int w = 0; w < 16; ++w) total += wsum[w];
        if (total < RANK_K) hi = mid; else lo = mid + 1;
        __syncthreads();
    }

    if (t == 0) thrOut[0] = __uint_as_float(lo);
    float4* m4 = (float4*)maskOut;
    #pragma unroll
    for (int i = 0; i < 16; ++i) {
        float4 m;
        m.x = (key[i*4+0] > lo) ? 1.0f : 0.0f;
        m.y = (key[i*4+1] > lo) ? 1.0f : 0.0f;
        m.z = (key[i*4+2] > lo) ? 1.0f : 0.0f;
        m.w = (key[i*4+3] > lo) ? 1.0f : 0.0f;   // strict > like reference
        m4[i * 1024 + t] = m;
    }
}

// ============ layer 3: h3 = relu((h2*m2) @ W3[256x10] + b3), full row norms ============
__global__ __launch_bounds__(256)
void layer3_kernel(const float* __restrict__ h2, const float* __restrict__ W3,
                   const float* __restrict__ b3, const float* __restrict__ mask2,
                   float* __restrict__ h3, float* __restrict__ norms3)
{
    __shared__ float wT[10][260];   // transposed W3 for b128 broadcast reads
    __shared__ float red[64][5];

    const int t    = threadIdx.x;
    const int r    = t & 63;
    const int g    = t >> 6;          // 0..3 column groups (3,3,3,1)
    const int j0   = g * 3;
    const int nj   = (g == 3) ? 1 : 3;
    const int row0 = blockIdx.x * 64;
    const int row  = row0 + r;

    for (int e = t; e < 2560; e += 256) wT[e % 10][e / 10] = W3[e];
    __syncthreads();

    const float m = mask2[row];
    const float* hrow = h2 + (size_t)row * 256;

    float acc[3] = {0.0f, 0.0f, 0.0f};
    for (int k = 0; k < 256; k += 4) {
        float4 v = *(const float4*)(hrow + k);
        v.x *= m; v.y *= m; v.z *= m; v.w *= m;
        float4 w0 = *(const float4*)&wT[j0][k];
        acc[0] += v.x*w0.x + v.y*w0.y + v.z*w0.z + v.w*w0.w;
        if (nj > 1) {
            float4 w1 = *(const float4*)&wT[j0+1][k];
            acc[1] += v.x*w1.x + v.y*w1.y + v.z*w1.z + v.w*w1.w;
            float4 w2 = *(const float4*)&wT[j0+2][k];
            acc[2] += v.x*w2.x + v.y*w2.y + v.z*w2.z + v.w*w2.w;
        }
    }

    float ss = 0.0f;
    for (int jj = 0; jj < nj; ++jj) {
        float v = fmaxf(acc[jj] + b3[j0 + jj], 0.0f);
        h3[(size_t)row * 10 + j0 + jj] = v;
        ss += v * v;
    }
    red[r][g] = ss;
    __syncthreads();
    if (t < 64) {
        float s = red[t][0] + red[t][1] + red[t][2] + red[t][3];  // fixed order
        norms3[row0 + t] = (float)sqrt((double)s);
    }
}

// ============ layer 4: h4 = (h3*m3) @ W4[10x10] + b4 (no relu), norms ============
__global__ __launch_bounds__(256)
void layer4_kernel(const float* __restrict__ h3, const float* __restrict__ W4,
                   const float* __restrict__ b4, const float* __restrict__ mask3,
                   float* __restrict__ h4, float* __restrict__ norms4)
{
    __shared__ float w[100];
    __shared__ float bb[10];
    const int t = threadIdx.x;
    if (t < 100) w[t] = W4[t];
    if (t < 10)  bb[t] = b4[t];
    __syncthreads();

    const int row = blockIdx.x * 256 + t;
    const float m = mask3[row];
    const float* hr = h3 + (size_t)row * 10;
    float v[10];
    #pragma unroll
    for (int k = 0; k < 10; ++k) v[k] = hr[k] * m;

    float s = 0.0f;
    #pragma unroll
    for (int j = 0; j < 10; ++j) {
        float a = 0.0f;
        #pragma unroll
        for (int k = 0; k < 10; ++k) a = fmaf(v[k], w[k*10 + j], a);
        a += bb[j];                     // dot then +bias (matches ref)
        h4[(size_t)row * 10 + j] = a;
        s = fmaf(a, a, s);
    }
    norms4[row] = (float)sqrt((double)s);
}

// ============ final: out = softmax(h4 * m4) ============
__global__ __launch_bounds__(256)
void softmax_kernel(const float* __restrict__ h4, const float* __restrict__ mask4,
                    float* __restrict__ out)
{
    const int t   = threadIdx.x;
    const int row = blockIdx.x * 256 + t;
    const float m = mask4[row];
    const float* hr = h4 + (size_t)row * 10;
    float v[10];
    #pragma unroll
    for (int k = 0; k < 10; ++k) v[k] = hr[k] * m;
    float mx = v[0];
    #pragma unroll
    for (int k = 1; k < 10; ++k) mx = fmaxf(mx, v[k]);
    float e[10];
    float s = 0.0f;
    #pragma unroll
    for (int k = 0; k < 10; ++k) { e[k] = expf(v[k] - mx); s += e[k]; }
    const float inv = 1.0f / s;
    #pragma unroll
    for (int k = 0; k < 10; ++k) out[(size_t)row * 10 + k] = e[k] * inv;
}

extern "C" void kernel_launch(void* const* d_in, const int* in_sizes, int n_in,
                              void* d_out, int out_size, void* d_ws, size_t ws_size,
                              hipStream_t stream)
{
    const float* x  = (const float*)d_in[0];
    const float* W1 = (const float*)d_in[1];
    const float* b1 = (const float*)d_in[2];
    const float* W2 = (const float*)d_in[3];
    const float* b2 = (const float*)d_in[4];
    const float* W3 = (const float*)d_in[5];
    const float* b3 = (const float*)d_in[6];
    const float* W4 = (const float*)d_in[7];
    const float* b4 = (const float*)d_in[8];

    float* out = (float*)d_out;                 // [65536,10]
    float* m1  = out + (size_t)BATCH * 10;      // [65536] each
    float* m2  = m1 + BATCH;
    float* m3  = m2 + BATCH;
    float* m4  = m3 + BATCH;

    float* ws    = (float*)d_ws;
    float* h1    = ws;                                  // 65536*512
    float* h2    = h1 + (size_t)BATCH * 512;            // 65536*256
    float* h3    = h2 + (size_t)BATCH * 256;            // 65536*10
    float* h4    = h3 + (size_t)BATCH * 10;             // 65536*10
    float* n1    = h4 + (size_t)BATCH * 10;             // 65536 x4 (n1/n2 unused)
    float* n2    = n1 + BATCH;
    float* n3    = n2 + BATCH;
    float* n4    = n3 + BATCH;
    float* part  = n4 + BATCH;                          // 4*65536
    float* thr   = part + (size_t)4 * BATCH;            // 4

    // layer 1: x[65536,784] @ W1[784,512]  (BN=128 -> 4 y-blocks -> partials 0..3 as validated)
    gemm_relu_norm<false><<<dim3(256, 4), 256, 0, stream>>>(x, W1, b1, nullptr, h1, part, 512, 784);
    select_kernel<4><<<1, 1024, 0, stream>>>(part, m1, thr + 0);

    // layer 2: (h1*m1)[65536,512] @ W2[512,256]  (mask applied in epilogue, exact)
    gemm_relu_norm<true><<<dim3(256, 2), 256, 0, stream>>>(h1, W2, b2, m1, h2, part, 256, 512);
    select_kernel<2><<<1, 1024, 0, stream>>>(part, m2, thr + 1);

    // layer 3: (h2*m2)[65536,256] @ W3[256,10]
    layer3_kernel<<<1024, 256, 0, stream>>>(h2, W3, b3, m2, h3, n3);
    select_kernel<0><<<1, 1024, 0, stream>>>(n3, m3, thr + 2);

    // layer 4: (h3*m3)[65536,10] @ W4[10,10] (no relu)
    layer4_kernel<<<256, 256, 0, stream>>>(h3, W4, b4, m3, h4, n4);
    select_kernel<0><<<1, 1024, 0, stream>>>(n4, m4, thr + 3);

    // softmax(h4*m4)
    softmax_kernel<<<256, 256, 0, stream>>>(h4, m4, out);
}

// Round 9
// 1321.617 us; speedup vs baseline: 1.0162x; 1.0162x over previous
//
#include <hip/hip_runtime.h>
#include <cstdint>
#include <cstddef>

#define BATCH   65536
#define RANK_K  32769   // sorted_desc[32768] == 32769-th largest (1-indexed)

// ============ big GEMM (layers 1&2): C = relu((A @ B)*rowmask + bias), + per-row sum-of-squares partials ============
// v9: BM=256, BN=128, **512 threads**, 8x8 per thread -> acc=64, total regs ~120 <= 128
//     -> __launch_bounds__(512,4) = 4 waves/SIMD (2 blocks/CU), DOUBLE the TLP of all prior variants.
//   Rationale: r0-r8 showed VALU-issue cycles constant (~1.05M/SIMD, 803k FMA) across every staging/
//   pipelining structure; the ~40% idle is co-stall of the only 2 resident waves/SIMD (16x8's 212-reg
//   footprint).  Smaller acc is the one untried lever: more waves to decorrelate stall windows.
//   Staging: v3's proven simple form (global->reg->ds_write, 2 barriers/tile).  B keeps v3's validated
//   granule swizzle; A-reads hit 4 distinct even bank-quads (conflict-free, 16-lane broadcast).
//   #pragma unroll 2 caps live fragments at 32 floats (v5/v6 lesson; 64 acc + 32 frag + ~25 addr <= 128).
// BIT-EXACTNESS: per-element k-chain = ascending k, single-register fmaf (identical to validated r0);
// thread's 8 cols = exactly one old col-group (cols tc*8..+7, tc 0..15) -> identical bias->relu->square
// chains and identical red[256][17] slots/order; layer-2 mask in EPILOGUE (m in {0,1}) validated
// bit-exact in rounds 6/8.  Masks cannot flip.
template<bool MASKED>
__global__ __launch_bounds__(512, 4)
void gemm_relu_norm(const float* __restrict__ A, const float* __restrict__ B,
                    const float* __restrict__ bias, const float* __restrict__ mask,
                    float* __restrict__ C, float* __restrict__ normPart,
                    const int N, const int K)
{
    __shared__ float As[16][260];   // [k][row], padded (24.8 KB total with Bs)
    __shared__ float Bs[16][128];   // [k][col], granule-swizzled

    const int t    = threadIdx.x;   // 0..511
    const int tr   = t >> 4;        // 0..31 row group (8 rows each)
    const int tc   = t & 15;        // 0..15 col group (8 cols each) == old col grouping
    const int row0 = blockIdx.x * 256;
    const int col0 = blockIdx.y * 128;

    // A staging: thread loads row t>>1, k-half (t&1)*8 (8 consecutive floats)
    const int arow = t >> 1;
    const int akb  = (t & 1) * 8;
    const float* Aptr = A + (size_t)(row0 + arow) * K + akb;

    // B staging: thread loads B[t>>5][col0 + (t&31)*4 .. +3]; store swizzled:
    // chunk c stored at float-offset (4c) ^ (((c>>4)&1)<<2)  (matches read side below)
    const int brow = t >> 5;
    const int bch  = t & 31;
    const float* Bptr = B + (size_t)brow * N + col0 + bch * 4;
    const int bst  = (bch * 4) ^ (((bch >> 4) & 1) << 2);

    // B read offsets (involution with store side -- v3-validated formula)
    const int bsw   = ((tc >> 3) & 1) << 2;
    const int bo_lo = (tc * 8) ^ bsw;
    const int bo_hi = (tc * 8 + 4) ^ bsw;

    float acc[8][8];
    #pragma unroll
    for (int i = 0; i < 8; ++i)
        #pragma unroll
        for (int j = 0; j < 8; ++j) acc[i][j] = 0.0f;

    for (int k0 = 0; k0 < K; k0 += 16) {
        // ---- load current tile (A: 8 floats, B: 4 floats per thread), stage to LDS ----
        float4 a0 = *(const float4*)(Aptr + k0);
        float4 a1 = *(const float4*)(Aptr + k0 + 4);
        float4 b0 = *(const float4*)(Bptr + (size_t)k0 * N);
        As[akb + 0][arow] = a0.x; As[akb + 1][arow] = a0.y;
        As[akb + 2][arow] = a0.z; As[akb + 3][arow] = a0.w;
        As[akb + 4][arow] = a1.x; As[akb + 5][arow] = a1.y;
        As[akb + 6][arow] = a1.z; As[akb + 7][arow] = a1.w;
        *(float4*)&Bs[brow][bst] = b0;
        __syncthreads();

        // ---- compute: 8x8, fragments 16 floats/kk; unroll 2 keeps liveness <= 32 ----
        #pragma unroll 2
        for (int kk = 0; kk < 16; ++kk) {
            float a_[8], b_[8];
            *(float4*)&a_[0] = *(const float4*)&As[kk][tr * 8];
            *(float4*)&a_[4] = *(const float4*)&As[kk][tr * 8 + 4];
            *(float4*)&b_[0] = *(const float4*)&Bs[kk][bo_lo];
            *(float4*)&b_[4] = *(const float4*)&Bs[kk][bo_hi];
            #pragma unroll
            for (int i = 0; i < 8; ++i)
                #pragma unroll
                for (int j = 0; j < 8; ++j)
                    acc[i][j] = fmaf(a_[i], b_[j], acc[i][j]);   // k ascending, single-reg chain
        }
        __syncthreads();
    }

    float bv[8];
    #pragma unroll
    for (int j = 0; j < 8; ++j) bv[j] = bias[col0 + tc * 8 + j];

    float mrow[8];
    if (MASKED) {
        *(float4*)&mrow[0] = *(const float4*)&mask[row0 + tr * 8];
        *(float4*)&mrow[4] = *(const float4*)&mask[row0 + tr * 8 + 4];
    }

    // bias -> relu -> square, chains identical to validated kernel (j ascending within the group)
    float rowsum[8];
    #pragma unroll
    for (int i = 0; i < 8; ++i) {
        float s = 0.0f;
        #pragma unroll
        for (int j = 0; j < 8; ++j) {
            float pv = MASKED ? acc[i][j] * mrow[i] : acc[i][j];  // exact: m in {0,1} (r6/r8-validated)
            float v  = fmaxf(pv + bv[j], 0.0f);
            acc[i][j] = v;
            s = fmaf(v, v, s);
        }
        rowsum[i] = s;
    }

    #pragma unroll
    for (int i = 0; i < 8; ++i) {
        const size_t row = (size_t)(row0 + tr * 8 + i);
        *(float4*)&C[row * N + col0 + tc * 8]     = *(float4*)&acc[i][0];
        *(float4*)&C[row * N + col0 + tc * 8 + 4] = *(float4*)&acc[i][4];
    }

    // red aliases the (now dead) As/Bs: 256*17*4 = 17408 B <= 24832 B.
    // All waves passed the loop's final barrier -> no one reads As/Bs anymore.
    float (*red)[17] = (float (*)[17])(&As[0][0]);
    #pragma unroll
    for (int i = 0; i < 8; ++i) red[tr * 8 + i][tc] = rowsum[i];
    __syncthreads();
    if (t < 256) {
        float s = 0.0f;
        #pragma unroll
        for (int x = 0; x < 16; ++x) s += red[t][x];    // fixed ascending order -> deterministic
        normPart[(size_t)blockIdx.y * BATCH + row0 + t] = s;
    }
}

// ============ fused: partial-sum -> norm -> exact 32769-th-largest -> mask ============
// NPART>=1: src = part[NPART][BATCH]; norm = sqrt((double)sum_p part[p][i]), p ascending
//           (chain identical to the old reduce_norms_kernel -> bit-identical norms).
// NPART==0: src = norms (already sqrt'd by layer3/layer4 kernels), used directly.
template<int NPART>
__global__ __launch_bounds__(1024)
void select_kernel(const float* __restrict__ src, float* __restrict__ maskOut,
                   float* __restrict__ thrOut)
{
    __shared__ int wsum[16];

    const int t = threadIdx.x;
    unsigned key[64];
    #pragma unroll
    for (int i = 0; i < 16; ++i) {
        float4 v;
        if (NPART == 0) {
            v = ((const float4*)src)[i * 1024 + t];
        } else {
            float4 s = ((const float4*)src)[i * 1024 + t];
            #pragma unroll
            for (int p = 1; p < NPART; ++p) {
                float4 w = ((const float4*)(src + (size_t)p * BATCH))[i * 1024 + t];
                s.x += w.x; s.y += w.y; s.z += w.z; s.w += w.w;   // p ascending, matches old
            }
            v.x = (float)sqrt((double)s.x);
            v.y = (float)sqrt((double)s.y);
            v.z = (float)sqrt((double)s.z);
            v.w = (float)sqrt((double)s.w);
        }
        key[i*4+0] = __float_as_uint(v.x);
        key[i*4+1] = __float_as_uint(v.y);
        key[i*4+2] = __float_as_uint(v.z);
        key[i*4+3] = __float_as_uint(v.w);      // nonneg floats -> monotone uint order
    }

    // V = min{ T : count(key > T) < RANK_K }  == exact RANK_K-th largest value
    unsigned lo = 0u, hi = 0x7F800000u;
    while (lo < hi) {                            // uniform across all threads
        const unsigned mid = lo + ((hi - lo) >> 1);
        int c = 0;
        #pragma unroll
        for (int i = 0; i < 64; ++i) c += (key[i] > mid) ? 1 : 0;
        #pragma unroll
        for (int off = 32; off > 0; off >>= 1) c += __shfl_down(c, off, 64);
        if ((t & 63) == 0) wsum[t >> 6] = c;
        __syncthreads();
        int total = 0;
        #pragma unroll
        for (int w = 0; w < 16; ++w) total += wsum[w];
        if (total < RANK_K) hi = mid; else lo = mid + 1;
        __syncthreads();
    }

    if (t == 0) thrOut[0] = __uint_as_float(lo);
    float4* m4 = (float4*)maskOut;
    #pragma unroll
    for (int i = 0; i < 16; ++i) {
        float4 m;
        m.x = (key[i*4+0] > lo) ? 1.0f : 0.0f;
        m.y = (key[i*4+1] > lo) ? 1.0f : 0.0f;
        m.z = (key[i*4+2] > lo) ? 1.0f : 0.0f;
        m.w = (key[i*4+3] > lo) ? 1.0f : 0.0f;   // strict > like reference
        m4[i * 1024 + t] = m;
    }
}

// ============ layer 3: h3 = relu((h2*m2) @ W3[256x10] + b3), full row norms ============
__global__ __launch_bounds__(256)
void layer3_kernel(const float* __restrict__ h2, const float* __restrict__ W3,
                   const float* __restrict__ b3, const float* __restrict__ mask2,
                   float* __restrict__ h3, float* __restrict__ norms3)
{
    __shared__ float wT[10][260];   // transposed W3 for b128 broadcast reads
    __shared__ float red[64][5];

    const int t    = threadIdx.x;
    const int r    = t & 63;
    const int g    = t >> 6;          // 0..3 column groups (3,3,3,1)
    const int j0   = g * 3;
    const int nj   = (g == 3) ? 1 : 3;
    const int row0 = blockIdx.x * 64;
    const int row  = row0 + r;

    for (int e = t; e < 2560; e += 256) wT[e % 10][e / 10] = W3[e];
    __syncthreads();

    const float m = mask2[row];
    const float* hrow = h2 + (size_t)row * 256;

    float acc[3] = {0.0f, 0.0f, 0.0f};
    for (int k = 0; k < 256; k += 4) {
        float4 v = *(const float4*)(hrow + k);
        v.x *= m; v.y *= m; v.z *= m; v.w *= m;
        float4 w0 = *(const float4*)&wT[j0][k];
        acc[0] += v.x*w0.x + v.y*w0.y + v.z*w0.z + v.w*w0.w;
        if (nj > 1) {
            float4 w1 = *(const float4*)&wT[j0+1][k];
            acc[1] += v.x*w1.x + v.y*w1.y + v.z*w1.z + v.w*w1.w;
            float4 w2 = *(const float4*)&wT[j0+2][k];
            acc[2] += v.x*w2.x + v.y*w2.y + v.z*w2.z + v.w*w2.w;
        }
    }

    float ss = 0.0f;
    for (int jj = 0; jj < nj; ++jj) {
        float v = fmaxf(acc[jj] + b3[j0 + jj], 0.0f);
        h3[(size_t)row * 10 + j0 + jj] = v;
        ss += v * v;
    }
    red[r][g] = ss;
    __syncthreads();
    if (t < 64) {
        float s = red[t][0] + red[t][1] + red[t][2] + red[t][3];  // fixed order
        norms3[row0 + t] = (float)sqrt((double)s);
    }
}

// ============ layer 4: h4 = (h3*m3) @ W4[10x10] + b4 (no relu), norms ============
__global__ __launch_bounds__(256)
void layer4_kernel(const float* __restrict__ h3, const float* __restrict__ W4,
                   const float* __restrict__ b4, const float* __restrict__ mask3,
                   float* __restrict__ h4, float* __restrict__ norms4)
{
    __shared__ float w[100];
    __shared__ float bb[10];
    const int t = threadIdx.x;
    if (t < 100) w[t] = W4[t];
    if (t < 10)  bb[t] = b4[t];
    __syncthreads();

    const int row = blockIdx.x * 256 + t;
    const float m = mask3[row];
    const float* hr = h3 + (size_t)row * 10;
    float v[10];
    #pragma unroll
    for (int k = 0; k < 10; ++k) v[k] = hr[k] * m;

    float s = 0.0f;
    #pragma unroll
    for (int j = 0; j < 10; ++j) {
        float a = 0.0f;
        #pragma unroll
        for (int k = 0; k < 10; ++k) a = fmaf(v[k], w[k*10 + j], a);
        a += bb[j];                     // dot then +bias (matches ref)
        h4[(size_t)row * 10 + j] = a;
        s = fmaf(a, a, s);
    }
    norms4[row] = (float)sqrt((double)s);
}

// ============ final: out = softmax(h4 * m4) ============
__global__ __launch_bounds__(256)
void softmax_kernel(const float* __restrict__ h4, const float* __restrict__ mask4,
                    float* __restrict__ out)
{
    const int t   = threadIdx.x;
    const int row = blockIdx.x * 256 + t;
    const float m = mask4[row];
    const float* hr = h4 + (size_t)row * 10;
    float v[10];
    #pragma unroll
    for (int k = 0; k < 10; ++k) v[k] = hr[k] * m;
    float mx = v[0];
    #pragma unroll
    for (int k = 1; k < 10; ++k) mx = fmaxf(mx, v[k]);
    float e[10];
    float s = 0.0f;
    #pragma unroll
    for (int k = 0; k < 10; ++k) { e[k] = expf(v[k] - mx); s += e[k]; }
    const float inv = 1.0f / s;
    #pragma unroll
    for (int k = 0; k < 10; ++k) out[(size_t)row * 10 + k] = e[k] * inv;
}

extern "C" void kernel_launch(void* const* d_in, const int* in_sizes, int n_in,
                              void* d_out, int out_size, void* d_ws, size_t ws_size,
                              hipStream_t stream)
{
    const float* x  = (const float*)d_in[0];
    const float* W1 = (const float*)d_in[1];
    const float* b1 = (const float*)d_in[2];
    const float* W2 = (const float*)d_in[3];
    const float* b2 = (const float*)d_in[4];
    const float* W3 = (const float*)d_in[5];
    const float* b3 = (const float*)d_in[6];
    const float* W4 = (const float*)d_in[7];
    const float* b4 = (const float*)d_in[8];

    float* out = (float*)d_out;                 // [65536,10]
    float* m1  = out + (size_t)BATCH * 10;      // [65536] each
    float* m2  = m1 + BATCH;
    float* m3  = m2 + BATCH;
    float* m4  = m3 + BATCH;

    float* ws    = (float*)d_ws;
    float* h1    = ws;                                  // 65536*512
    float* h2    = h1 + (size_t)BATCH * 512;            // 65536*256
    float* h3    = h2 + (size_t)BATCH * 256;            // 65536*10
    float* h4    = h3 + (size_t)BATCH * 10;             // 65536*10
    float* n1    = h4 + (size_t)BATCH * 10;             // 65536 x4 (n1/n2 unused)
    float* n2    = n1 + BATCH;
    float* n3    = n2 + BATCH;
    float* n4    = n3 + BATCH;
    float* part  = n4 + BATCH;                          // 4*65536
    float* thr   = part + (size_t)4 * BATCH;            // 4

    // layer 1: x[65536,784] @ W1[784,512]  (BN=128 -> 4 y-blocks -> partials 0..3 as validated)
    gemm_relu_norm<false><<<dim3(256, 4), 512, 0, stream>>>(x, W1, b1, nullptr, h1, part, 512, 784);
    select_kernel<4><<<1, 1024, 0, stream>>>(part, m1, thr + 0);

    // layer 2: (h1*m1)[65536,512] @ W2[512,256]  (mask applied in epilogue, exact)
    gemm_relu_norm<true><<<dim3(256, 2), 512, 0, stream>>>(h1, W2, b2, m1, h2, part, 256, 512);
    select_kernel<2><<<1, 1024, 0, stream>>>(part, m2, thr + 1);

    // layer 3: (h2*m2)[65536,256] @ W3[256,10]
    layer3_kernel<<<1024, 256, 0, stream>>>(h2, W3, b3, m2, h3, n3);
    select_kernel<0><<<1, 1024, 0, stream>>>(n3, m3, thr + 2);

    // layer 4: (h3*m3)[65536,10] @ W4[10,10] (no relu)
    layer4_kernel<<<256, 256, 0, stream>>>(h3, W4, b4, m3, h4, n4);
    select_kernel<0><<<1, 1024, 0, stream>>>(n4, m4, thr + 3);

    // softmax(h4*m4)
    softmax_kernel<<<256, 256, 0, stream>>>(h4, m4, out);
}